// Round 13
// baseline (71.851 us; speedup 1.0000x reference)
//
#include <hip/hip_runtime.h>
#include <hip/hip_bf16.h>

#define B_ 8
#define T_ 2048
#define D_ 128

typedef __attribute__((ext_vector_type(8))) short short8;
typedef __attribute__((ext_vector_type(4))) short s16x4;
typedef __attribute__((ext_vector_type(4))) float f32x4;

static __device__ __forceinline__ short f2bf(float f) {
  __hip_bfloat16 h = __float2bfloat16(f);
  return *reinterpret_cast<short*>(&h);
}

// scale * log2(e):  (1/sqrt(128)) * 1.4426950408889634
#define SL 0.12754434770570355f

// q-supertile = 128 rows (4 waves x 32). ns(qt)=qt+1 splits x 4 KV-tiles.
// UPB = sum_{qt=0..15} (qt+1) = 136.
#define UPB 136

// direct global->LDS, 16B per lane (dest = wave-uniform base + lane*16)
static __device__ __forceinline__ void gl_lds16(const void* g, void* l) {
  __builtin_amdgcn_global_load_lds(
      (const __attribute__((address_space(1))) unsigned*)g,
      (__attribute__((address_space(3))) unsigned*)l, 16, 0, 0);
}

// ---------------------------------------------------------------------------
// Kernel 0: W [128][128] f32 -> W^T [128][128] bf16.
__global__ void wtrans_kernel(const float* __restrict__ Wq, const float* __restrict__ Wk,
                              const float* __restrict__ Wv, __hip_bfloat16* __restrict__ WT) {
  const float* W = (blockIdx.y == 0) ? Wq : (blockIdx.y == 1) ? Wk : Wv;
  int n = blockIdx.x, k = threadIdx.x;
  WT[((size_t)blockIdx.y * 128 + n) * 128 + k] = __float2bfloat16(W[k * 128 + n]);
}

// ---------------------------------------------------------------------------
// Kernel 1: projections, one matrix per blockIdx.y.
// q,k row-major bf16; v stored TRANSPOSED [B][D][T].
__global__ __launch_bounds__(256) void proj_kernel(const float* __restrict__ x,
    const __hip_bfloat16* __restrict__ WT,
    __hip_bfloat16* __restrict__ qp, __hip_bfloat16* __restrict__ kp,
    __hip_bfloat16* __restrict__ vpT) {
  const int wv = threadIdx.x >> 6, lane = threadIdx.x & 63;
  const int ar = lane & 15, kg = lane >> 4;
  const int row0 = blockIdx.x * 64 + wv * 16;
  const int b = row0 >> 11, tloc = row0 & 2047;
  const int m = blockIdx.y;

  short8 a[4];
  {
    const float* px = x + (size_t)(row0 + ar) * 128 + kg * 8;
#pragma unroll
    for (int ks = 0; ks < 4; ++ks) {
      const float* p = px + ks * 32;
      f32x4 x0 = *(const f32x4*)p;
      f32x4 x1 = *(const f32x4*)(p + 4);
      short8 t;
      t[0] = f2bf(x0[0]); t[1] = f2bf(x0[1]); t[2] = f2bf(x0[2]); t[3] = f2bf(x0[3]);
      t[4] = f2bf(x1[0]); t[5] = f2bf(x1[1]); t[6] = f2bf(x1[2]); t[7] = f2bf(x1[3]);
      a[ks] = t;
    }
  }
  const __hip_bfloat16* wt = WT + (size_t)m * 128 * 128;
  if (m < 2) {
    __hip_bfloat16* outp = (m == 0) ? qp : kp;
#pragma unroll
    for (int nt = 0; nt < 8; ++nt) {
      f32x4 acc = {0.f, 0.f, 0.f, 0.f};
#pragma unroll
      for (int ks = 0; ks < 4; ++ks) {
        short8 bfr = *(const short8*)(wt + (nt * 16 + ar) * 128 + ks * 32 + kg * 8);
        acc = __builtin_amdgcn_mfma_f32_16x16x32_bf16(a[ks], bfr, acc, 0, 0, 0);
      }
#pragma unroll
      for (int r = 0; r < 4; ++r)
        outp[(size_t)(row0 + kg * 4 + r) * 128 + nt * 16 + ar] = __float2bfloat16(acc[r]);
    }
  } else {
#pragma unroll
    for (int nt = 0; nt < 8; ++nt) {
      f32x4 acc = {0.f, 0.f, 0.f, 0.f};
#pragma unroll
      for (int ks = 0; ks < 4; ++ks) {
        short8 wfr = *(const short8*)(wt + (nt * 16 + ar) * 128 + ks * 32 + kg * 8);
        acc = __builtin_amdgcn_mfma_f32_16x16x32_bf16(wfr, a[ks], acc, 0, 0, 0);
      }
#pragma unroll
      for (int r = 0; r < 4; ++r)
        vpT[((size_t)b * 128 + nt * 16 + kg * 4 + r) * 2048 + tloc + ar] = __float2bfloat16(acc[r]);
    }
  }
}

// ---------------------------------------------------------------------------
// Kernel 2: causal flash attention (roles swapped: Q'=k_proj, K'=q_proj).
// 4 waves x 32 q-rows share one 128-row Q-tile (halves redundant K/V LDS
// reads vs 8x16). K/V in a 4-deep LDS ring via global_load_lds; counted
// vmcnt barriers. Fixed-m softmax (m=0). 4 KV-tiles per block.
__global__ __launch_bounds__(256, 2) void attn_kernel(const __hip_bfloat16* __restrict__ qp,
    const __hip_bfloat16* __restrict__ kp, const __hip_bfloat16* __restrict__ vpT,
    float* __restrict__ out, __hip_bfloat16* __restrict__ po, float* __restrict__ pml,
    int chunked) {
  const int bid = blockIdx.x;
  const int b = bid & 7;            // batch -> XCD pinning
  const int u = bid >> 3;
  int qt, s, ns;
  if (chunked) {
    int g = 0;
#pragma unroll
    for (int i = 1; i < 16; ++i)
      if (u >= (i * (i + 1)) / 2) g = i;
    qt = g; s = u - (g * (g + 1)) / 2; ns = g + 1;
  } else {
    qt = u; s = 0; ns = 1;
  }
  const int wv = threadIdx.x >> 6, lane = threadIdx.x & 63;
  const int ar = lane & 15, kg = lane >> 4;

  // KV ring: 4 slots x [frag(16)][lane(64) x 16B]; frags 0-7 = K, 8-15 = V
  __shared__ short KV[4][8192];
  __shared__ short Pl[4][32][52];
  short (*Plw)[52] = Pl[wv];

  const int qrow0 = qt * 128 + wv * 32;    // 32 rows per wave
  const size_t boff = (size_t)b * T_ * 128;
  const size_t bvoff = (size_t)b * 128 * 2048;

  // Q fragments: two 16-row groups
  short8 qf[2][4];
#pragma unroll
  for (int g = 0; g < 2; ++g) {
    const __hip_bfloat16* qb = kp + boff + (size_t)(qrow0 + g * 16 + ar) * 128 + kg * 8;
#pragma unroll
    for (int ks = 0; ks < 4; ++ks) qf[g][ks] = *(const short8*)(qb + ks * 32);
  }

  f32x4 o[2][8];
  {
    f32x4 z = {0.f, 0.f, 0.f, 0.f};
#pragma unroll
    for (int g = 0; g < 2; ++g)
#pragma unroll
      for (int i = 0; i < 8; ++i) o[g][i] = z;
  }
  float lpart[2][4] = {{0.f, 0.f, 0.f, 0.f}, {0.f, 0.f, 0.f, 0.f}};

  const int t0 = chunked ? s * 4 : 0;
  const int n = chunked ? 4 : (4 * qt + 4);

  // staging sources: wave wv stages K-frags {2wv,2wv+1} and V-frags {2wv,2wv+1}
  // K frag f: lane holds K[token (f>>2)*16+ar][depth (f&3)*32+kg*8]
  const int fA = 2 * wv, fB = 2 * wv + 1;
  const __hip_bfloat16* KsrcA = qp + boff + (size_t)((fA >> 2) * 16 + ar) * 128 + (fA & 3) * 32 + kg * 8;
  const __hip_bfloat16* KsrcB = qp + boff + (size_t)((fB >> 2) * 16 + ar) * 128 + (fB & 3) * 32 + kg * 8;
  // V frag f: lane holds V^T[d f*16+ar][kv kg*8..]
  const __hip_bfloat16* VsrcA = vpT + bvoff + (size_t)(fA * 16 + ar) * 2048 + kg * 8;
  const __hip_bfloat16* VsrcB = vpT + bvoff + (size_t)(fB * 16 + ar) * 2048 + kg * 8;

  // prologue: stage tiles t0, t0+1 into ring slots 0,1 (4 loads per wave each)
  gl_lds16(KsrcA + (size_t)t0 * 4096, &KV[0][fA * 512]);
  gl_lds16(KsrcB + (size_t)t0 * 4096, &KV[0][fB * 512]);
  gl_lds16(VsrcA + (size_t)t0 * 32, &KV[0][(8 + fA) * 512]);
  gl_lds16(VsrcB + (size_t)t0 * 32, &KV[0][(8 + fB) * 512]);
  if (n > 1) {
    gl_lds16(KsrcA + (size_t)(t0 + 1) * 4096, &KV[1][fA * 512]);
    gl_lds16(KsrcB + (size_t)(t0 + 1) * 4096, &KV[1][fB * 512]);
    gl_lds16(VsrcA + (size_t)(t0 + 1) * 32, &KV[1][(8 + fA) * 512]);
    gl_lds16(VsrcB + (size_t)(t0 + 1) * 32, &KV[1][(8 + fB) * 512]);
  }

  for (int i = 0; i < n; ++i) {
    const int t = t0 + i;
    if (i + 2 < n) {   // prefetch tile t+2 into ring slot (i+2)&3
      short* slot = KV[(i + 2) & 3];
      gl_lds16(KsrcA + (size_t)(t + 2) * 4096, &slot[fA * 512]);
      gl_lds16(KsrcB + (size_t)(t + 2) * 4096, &slot[fB * 512]);
      gl_lds16(VsrcA + (size_t)(t + 2) * 32, &slot[(8 + fA) * 512]);
      gl_lds16(VsrcB + (size_t)(t + 2) * 32, &slot[(8 + fB) * 512]);
    }
    // counted wait: FIFO completion guarantees tile t's loads landed
    const int rem = n - 1 - i;
    if (rem >= 2)      asm volatile("s_waitcnt vmcnt(8)" ::: "memory");
    else if (rem == 1) asm volatile("s_waitcnt vmcnt(4)" ::: "memory");
    else               asm volatile("s_waitcnt vmcnt(0)" ::: "memory");
    __builtin_amdgcn_s_barrier();
    asm volatile("" ::: "memory");

    const short* buf = KV[i & 3];

    // --- QK: S = Q' K'^T for both row groups (K frags read once) ---
    f32x4 sc[2][2];
#pragma unroll
    for (int nt = 0; nt < 2; ++nt) {
#pragma unroll
      for (int g = 0; g < 2; ++g) {
        f32x4 acc = {0.f, 0.f, 0.f, 0.f};
        sc[g][nt] = acc;
      }
#pragma unroll
      for (int ks = 0; ks < 4; ++ks) {
        short8 kf = *(const short8*)&buf[(nt * 4 + ks) * 512 + lane * 8];
        sc[0][nt] = __builtin_amdgcn_mfma_f32_16x16x32_bf16(qf[0][ks], kf, sc[0][nt], 0, 0, 0);
        sc[1][nt] = __builtin_amdgcn_mfma_f32_16x16x32_bf16(qf[1][ks], kf, sc[1][nt], 0, 0, 0);
      }
    }

    // --- P = exp2(s*SL) (fixed m=0), mask only near/past diagonal ---
#pragma unroll
    for (int g = 0; g < 2; ++g) {
      const int rel = qrow0 + g * 16 - t * 32;   // wave-uniform
      if (rel >= 31) {
#pragma unroll
        for (int nt = 0; nt < 2; ++nt)
#pragma unroll
          for (int r = 0; r < 4; ++r) {
            float pe = exp2f(sc[g][nt][r] * SL);
            lpart[g][r] += pe;
            unsigned uu = __float_as_uint(pe) + 0x8000u;
            Plw[g * 16 + kg * 4 + r][nt * 16 + ar] = (short)(uu >> 16);
          }
      } else {
#pragma unroll
        for (int nt = 0; nt < 2; ++nt)
#pragma unroll
          for (int r = 0; r < 4; ++r) {
            float v = sc[g][nt][r];
            if (nt * 16 + ar - rel > kg * 4 + r) v = -3.0e38f;
            float pe = exp2f(v * SL);
            lpart[g][r] += pe;
            unsigned uu = __float_as_uint(pe) + 0x8000u;
            Plw[g * 16 + kg * 4 + r][nt * 16 + ar] = (short)(uu >> 16);
          }
      }
    }

    // --- PV: O += P @ V (V frags read once for both row groups) ---
    short8 pa0 = *(const short8*)&Plw[ar][kg * 8];
    short8 pa1 = *(const short8*)&Plw[16 + ar][kg * 8];
#pragma unroll
    for (int n8 = 0; n8 < 8; ++n8) {
      short8 vf = *(const short8*)&buf[(8 + n8) * 512 + lane * 8];
      o[0][n8] = __builtin_amdgcn_mfma_f32_16x16x32_bf16(pa0, vf, o[0][n8], 0, 0, 0);
      o[1][n8] = __builtin_amdgcn_mfma_f32_16x16x32_bf16(pa1, vf, o[1][n8], 0, 0, 0);
    }
  }

  // epilogue: reduce l across the 16 ar-lanes (once)
#pragma unroll
  for (int g = 0; g < 2; ++g)
#pragma unroll
    for (int r = 0; r < 4; ++r) {
      float v = lpart[g][r];
      v += __shfl_xor(v, 1);
      v += __shfl_xor(v, 2);
      v += __shfl_xor(v, 4);
      v += __shfl_xor(v, 8);
      lpart[g][r] = v;
    }

  if (ns == 1) {
#pragma unroll
    for (int g = 0; g < 2; ++g)
#pragma unroll
      for (int r = 0; r < 4; ++r) lpart[g][r] = 1.f / lpart[g][r];
#pragma unroll
    for (int g = 0; g < 2; ++g)
#pragma unroll
      for (int n8 = 0; n8 < 8; ++n8)
#pragma unroll
        for (int r = 0; r < 4; ++r)
          out[boff + (size_t)(qrow0 + g * 16 + kg * 4 + r) * 128 + n8 * 16 + ar] =
              o[g][n8][r] * lpart[g][r];
  } else {
    const int slot = b * UPB + u;
    __hip_bfloat16* pb = po + (size_t)slot * 128 * 128;
#pragma unroll
    for (int g = 0; g < 2; ++g)
#pragma unroll
      for (int n8 = 0; n8 < 8; ++n8)
#pragma unroll
        for (int r = 0; r < 4; ++r)
          pb[(wv * 32 + g * 16 + kg * 4 + r) * 128 + n8 * 16 + ar] = __float2bfloat16(o[g][n8][r]);
    if (ar == 0) {
#pragma unroll
      for (int g = 0; g < 2; ++g)
#pragma unroll
        for (int r = 0; r < 4; ++r)
          pml[slot * 128 + wv * 32 + g * 16 + kg * 4 + r] = lpart[g][r];
    }
  }
}

// ---------------------------------------------------------------------------
// Kernel 3: merge splits for supertiles qt >= 1 (rows 128..2047 per batch).
// Streaming sums (fixed-m: no max merge). thread = (b, row, 4-elem d chunk).
__global__ __launch_bounds__(256) void combine_kernel(const __hip_bfloat16* __restrict__ po,
    const float* __restrict__ pml, float* __restrict__ out) {
  const int g0 = blockIdx.x * 256 + threadIdx.x;
  const int c = g0 & 31;
  const int rowm = (g0 >> 5) % 1920;
  const int b = g0 / (1920 * 32);
  const int row = 128 + rowm;
  const int qt = row >> 7;
  const int ns = qt + 1;
  const int rowin = row & 127;
  const int slot0 = b * UPB + (qt * (qt + 1)) / 2;

  f32x4 num = {0.f, 0.f, 0.f, 0.f};
  float den = 0.f;
  for (int s = 0; s < ns; ++s) {
    den += pml[(slot0 + s) * 128 + rowin];
    s16x4 ov = *(const s16x4*)(po + (size_t)(slot0 + s) * 128 * 128 + rowin * 128 + c * 4);
#pragma unroll
    for (int i = 0; i < 4; ++i) {
      unsigned u = ((unsigned)(unsigned short)ov[i]) << 16;
      num[i] += __uint_as_float(u);
    }
  }
  float inv = 1.f / den;
  f32x4 res;
#pragma unroll
  for (int i = 0; i < 4; ++i) res[i] = num[i] * inv;
  *(f32x4*)(out + ((size_t)b * 2048 + row) * 128 + c * 4) = res;
}

// ---------------------------------------------------------------------------
extern "C" void kernel_launch(void* const* d_in, const int* in_sizes, int n_in,
                              void* d_out, int out_size, void* d_ws, size_t ws_size,
                              hipStream_t stream) {
  const float* x  = (const float*)d_in[0];
  const float* Wq = (const float*)d_in[1];
  const float* Wk = (const float*)d_in[2];
  const float* Wv = (const float*)d_in[3];
  float* out = (float*)d_out;

  char* ws = (char*)d_ws;
  __hip_bfloat16* WT  = (__hip_bfloat16*)ws;                        // 96 KB
  __hip_bfloat16* qp  = (__hip_bfloat16*)(ws + 98304);              // 4 MB
  __hip_bfloat16* kp  = qp + (size_t)B_ * T_ * 128;                 // 4 MB
  __hip_bfloat16* vpT = kp + (size_t)B_ * T_ * 128;                 // 4 MB
  __hip_bfloat16* po  = (__hip_bfloat16*)(ws + 98304 + 3 * (size_t)B_ * T_ * 128 * 2); // 34 MB
  const size_t nslot = (size_t)8 * UPB;                             // 1088
  float* pml = (float*)((char*)po + nslot * 128 * 128 * 2);         // 557 KB

  const size_t need = 98304 + 3 * (size_t)B_ * T_ * 128 * 2
                    + nslot * 128 * 128 * 2 + nslot * 128 * 4;
  const int chunked = (ws_size >= need) ? 1 : 0;

  wtrans_kernel<<<dim3(128, 3), 128, 0, stream>>>(Wq, Wk, Wv, WT);
  proj_kernel<<<dim3(256, 3), 256, 0, stream>>>(x, WT, qp, kp, vpT);
  if (chunked) {
    attn_kernel<<<8 * UPB, 256, 0, stream>>>(qp, kp, vpT, out, po, pml, 1);
    combine_kernel<<<1920, 256, 0, stream>>>(po, pml, out);
  } else {
    attn_kernel<<<128, 256, 0, stream>>>(qp, kp, vpT, out, po, pml, 0);
  }
}